// Round 9
// baseline (20694.412 us; speedup 1.0000x reference)
//
#include <hip/hip_runtime.h>
#include <stdint.h>

#define DD 200
#define MM 128
#define JJ 256
#define BB 32
#define TPB 1024
#define MEMSTRIDE 201

// Soft barrier: LDS visibility + execution sync, but does NOT drain vmcnt —
// global (weight) loads stay in flight across phase boundaries. Executed only
// in block-uniform control flow.
#define SOFTBAR() asm volatile("s_waitcnt lgkmcnt(0)\n\ts_barrier" ::: "memory")

// clang-native 16B vector; component access via [] only.
typedef float f4 __attribute__((ext_vector_type(4)));

__device__ inline float sigm(float x) { return 1.f / (1.f + expf(-x)); }

__device__ inline void fma4spread(float& a0, float& a1, float& a2, float& a3, f4 w, f4 v) {
  a0 = fmaf(w[0], v[0], a0); a1 = fmaf(w[1], v[1], a1);
  a2 = fmaf(w[2], v[2], a2); a3 = fmaf(w[3], v[3], a3);
}

__device__ inline float dot4acc(float acc, f4 w, f4 v) {
  acc = fmaf(w[0], v[0], acc); acc = fmaf(w[1], v[1], acc);
  acc = fmaf(w[2], v[2], acc); acc = fmaf(w[3], v[3], acc);
  return acc;
}

// ---- weight prep: transpose to k-major, pack fp32 QUADS along k ----

__global__ void pack_gates_w(const float* __restrict__ w_ih, const float* __restrict__ w_hh,
                             const float* __restrict__ b_ih, const float* __restrict__ b_hh,
                             float* __restrict__ Wg4, float* __restrict__ bg) {
  int idx = blockIdx.x * blockDim.x + threadIdx.x;
  if (idx < 100 * 800) {
    int k4 = idx / 800, g = idx - k4 * 800;
    #pragma unroll
    for (int e = 0; e < 4; ++e) {
      int k = 4 * k4 + e;
      Wg4[4 * idx + e] = (k < DD) ? w_ih[g * DD + k] : w_hh[g * DD + (k - DD)];
    }
  }
  if (idx < 800) bg[idx] = b_ih[idx] + b_hh[idx];
}

__global__ void pack_fc1(const float* __restrict__ w_fc1, float* __restrict__ Tfc14) {
  int idx = blockIdx.x * blockDim.x + threadIdx.x;
  if (idx < 100 * DD) {
    int k4 = idx / DD, d = idx - k4 * DD;
    const float* p = w_fc1 + d * 400 + 4 * k4;
    #pragma unroll
    for (int e = 0; e < 4; ++e) Tfc14[4 * idx + e] = p[e];
  }
}

__global__ void pack_fc(const float* __restrict__ w_fc, float* __restrict__ Tfc4) {
  int idx = blockIdx.x * blockDim.x + threadIdx.x;
  if (idx < 50 * DD) {
    int k4 = idx / DD, d = idx - k4 * DD;
    const float* p = w_fc + d * DD + 4 * k4;
    #pragma unroll
    for (int e = 0; e < 4; ++e) Tfc4[4 * idx + e] = p[e];
  }
}

// Ch chunk: waves 8-15 compute gh = W_hh . h for the NEXT p across E..H windows.
#define CH_CHUNK(A, B) { \
  const f4* qvh = reinterpret_cast<const f4*>(qh_s); \
  for (int kk = (A); kk < (B); ++kk) { \
    f4 v = qvh[50 + kk]; \
    f4 w0 = WgH[kk * 800]; \
    ch0 = dot4acc(ch0, w0, v); \
    if (hasB) { f4 w1 = WgH[kk * 800 + 512]; ch1 = dot4acc(ch1, w1, v); } \
  } \
}

// ---- main: one block per (b, parity) chain; mem resident in LDS ----
// TPB=1024 -> exactly 4 waves/SIMD, 1 block/CU (grid=64 on 256 CUs).
// amdgpu_waves_per_eu(4,4): budget VGPRs for exactly 4 waves/EU (128) instead
// of the heuristic 64 — rounds 7/8 showed the allocator pins 64 and spills.
__global__ __launch_bounds__(TPB) __attribute__((amdgpu_waves_per_eu(4, 4)))
void chain_kernel(const float* __restrict__ cosb, const float* __restrict__ bank,
                  const float* __restrict__ mem_a, const float* __restrict__ mem_b,
                  const float* __restrict__ b_fc, const float* __restrict__ b_fc1,
                  const f4* __restrict__ Wg4, const f4* __restrict__ Tfc14,
                  const f4* __restrict__ Tfc4, const float* __restrict__ bg,
                  float* __restrict__ out)
{
  extern __shared__ float mem_s[];               // [128][201] = 102,912 B
  __shared__ __align__(16) float qh_s[400];      // [0:200)=q, [200:400)=h
  __shared__ __align__(16) float xq_s[400];      // [200:400)=q_old (concat tail)
  __shared__ __align__(16) float qsv_s[DD];
  __shared__ __align__(16) float bank_sh[2][DD];
  __shared__ __align__(16) float q0_s[2][DD];
  __shared__ __align__(16) float cos_s[2][MM];
  __shared__ __align__(16) float gates_s[800];
  __shared__ __align__(16) float gh_s[800];      // W_hh.h for next p
  __shared__ __align__(16) float logp_s[512];
  __shared__ __align__(16) float hp_s[400];
  __shared__ __align__(16) float xp_s[400];
  __shared__ __align__(16) float fq_s[400];
  __shared__ __align__(16) float att_s[MM];

  const int t = threadIdx.x;
  const int par = blockIdx.x & 1;
  const int b = blockIdx.x >> 1;

  const f4* wpC = Wg4 + t;                       // valid for t<800
  const int khH = (t >= DD) ? 1 : 0;
  const int dH = t - khH * DD;                   // valid for t<400
  const f4* wpH2 = Tfc14 + dH + khH * 50 * DD;
  const f4* wpK2 = Tfc4 + dH + khH * 25 * DD;

  // Ch-worker mapping (waves 8-15): outputs gCh and gCh+512 (if <800)
  const int gCh = (t >= 512) ? (t - 512) : 0;
  const bool hasB = (t >= 512) && (gCh < 288);
  const f4* WgH = Wg4 + 50 * 800 + gCh;          // h-part base (k4 = 50..100)

  // prologue: load mem + stage step-0 cos/bank
  const float* msrc = (par ? mem_b : mem_a) + b * MM * DD;
  for (int i = t; i < MM * DD; i += TPB) {
    int m = i / DD, d = i - m * DD;
    mem_s[m * MEMSTRIDE + d] = msrc[i];
  }
  if (t < MM) cos_s[0][t] = cosb[(b * JJ + par) * MM + t];
  else if (t < MM + DD) bank_sh[0][t - MM] = bank[(par * BB + b) * DD + (t - MM)];
  __syncthreads();

  // q0 for step 0 (prologue only)
  if (t < DD) {
    float a0 = b_fc[t], a1 = 0.f, a2 = 0.f, a3 = 0.f;
    const f4* bv = reinterpret_cast<const f4*>(bank_sh[0]);
    const f4* wp = Tfc4 + t;
    #pragma unroll 5
    for (int k4 = 0; k4 < 50; ++k4) {
      fma4spread(a0, a1, a2, a3, wp[k4 * DD], bv[k4]);
    }
    q0_s[0][t] = (a0 + a1) + (a2 + a3);
  }
  __syncthreads();

  float c_reg = 0.f, sv_reg = 0.f;

  for (int s = 0; s < JJ / 2; ++s) {
    const int j = 2 * s + par;
    const int cur = s & 1, nxt = cur ^ 1;

    // Phase A: h0 partials (2-way m-split) | stage next cos/bank
    if (t < 400) {
      int half = (t >= DD) ? 1 : 0;
      int d = t - half * DD;
      const float* cs = cos_s[cur] + half * 64;
      const float* mp = mem_s + (half * 64) * MEMSTRIDE + d;
      float a0 = 0.f, a1 = 0.f;
      #pragma unroll 4
      for (int m = 0; m < 64; m += 2) {
        a0 = fmaf(cs[m], mp[m * MEMSTRIDE], a0);
        a1 = fmaf(cs[m + 1], mp[(m + 1) * MEMSTRIDE], a1);
      }
      hp_s[half * DD + d] = a0 + a1;
    } else if (t < 400 + MM + DD) {
      if (s + 1 < JJ / 2) {
        int u = t - 400, j2 = j + 2;
        if (u < MM) cos_s[nxt][u] = cosb[(b * JJ + j2) * MM + u];
        else bank_sh[nxt][u - MM] = bank[(j2 * BB + b) * DD + (u - MM)];
      }
    }
    SOFTBAR();

    // Phase B: reduce h partials, install q0
    if (t < DD) {
      float h = hp_s[t] + hp_s[DD + t];
      float q = q0_s[cur][t];
      qh_s[200 + t] = h;
      qh_s[t] = q;
      xq_s[200 + t] = q;
      c_reg = 0.f;
    }
    SOFTBAR();

    for (int p = 0; p < 3; ++p) {
      // Phase C: gates GEMV.
      //   p==0: full k (q-half + h-half), since h0 had no overlap window.
      //   p>0 : q-half only + gh_s (h-half precomputed during prev E..H).
      // Sideband (p==0, waves 13+): next-step q0.
      if (t < 800) {
        const f4* qv4 = reinterpret_cast<const f4*>(qh_s);
        if (p == 0) {
          float a0 = bg[t], a1 = 0.f, a2 = 0.f, a3 = 0.f;
          for (int k4 = 0; k4 < 100; k4 += 4) {
            f4 w0 = wpC[k4 * 800], w1 = wpC[(k4 + 1) * 800];
            f4 w2 = wpC[(k4 + 2) * 800], w3 = wpC[(k4 + 3) * 800];
            a0 = dot4acc(a0, w0, qv4[k4]);
            a1 = dot4acc(a1, w1, qv4[k4 + 1]);
            a2 = dot4acc(a2, w2, qv4[k4 + 2]);
            a3 = dot4acc(a3, w3, qv4[k4 + 3]);
          }
          gates_s[t] = (a0 + a1) + (a2 + a3);
        } else {
          float a0 = bg[t] + gh_s[t], a1 = 0.f, a2 = 0.f, a3 = 0.f;
          for (int k4 = 0; k4 < 48; k4 += 4) {
            f4 w0 = wpC[k4 * 800], w1 = wpC[(k4 + 1) * 800];
            f4 w2 = wpC[(k4 + 2) * 800], w3 = wpC[(k4 + 3) * 800];
            a0 = dot4acc(a0, w0, qv4[k4]);
            a1 = dot4acc(a1, w1, qv4[k4 + 1]);
            a2 = dot4acc(a2, w2, qv4[k4 + 2]);
            a3 = dot4acc(a3, w3, qv4[k4 + 3]);
          }
          a0 = dot4acc(a0, wpC[48 * 800], qv4[48]);
          a1 = dot4acc(a1, wpC[49 * 800], qv4[49]);
          gates_s[t] = (a0 + a1) + (a2 + a3);
        }
      } else if (p == 0 && t >= 832 && s + 1 < JJ / 2) {
        int u = t - 832;
        for (int d = u; d < DD; d += 192) {
          float a0 = b_fc[d], a1 = 0.f, a2 = 0.f, a3 = 0.f;
          const f4* bv = reinterpret_cast<const f4*>(bank_sh[nxt]);
          const f4* wp = Tfc4 + d;
          #pragma unroll 5
          for (int k4 = 0; k4 < 50; ++k4) {
            fma4spread(a0, a1, a2, a3, wp[k4 * DD], bv[k4]);
          }
          q0_s[nxt][d] = (a0 + a1) + (a2 + a3);
        }
      }
      SOFTBAR();

      // Phase D: LSTM cell — produces h for THIS p's attention and for the
      // NEXT p's gates (Ch overlap below).
      if (t < DD) {
        float ig = gates_s[t], fg = gates_s[200 + t], gg = gates_s[400 + t], og = gates_s[600 + t];
        c_reg = sigm(fg) * c_reg + sigm(ig) * tanhf(gg);
        float h = sigm(og) * tanhf(c_reg);
        qh_s[200 + t] = h;
        xq_s[200 + t] = qh_s[t];   // stash current q for the concat
      }
      SOFTBAR();

      // Ch accumulators (waves 8-15), live across E..H
      float ch0 = 0.f, ch1 = 0.f;

      // Phase E: logits (512 threads, 4-way d-split, wave-uniform) | Ch chunk 1
      if (t < 512) {
        int qd = t >> 7, m = t & 127;
        const float* hv = qh_s + 200 + qd * 50;
        const float* mrow = mem_s + m * MEMSTRIDE + qd * 50;
        float l0 = 0.f, l1 = 0.f;
        #pragma unroll
        for (int d = 0; d < 50; d += 2) {
          l0 = fmaf(hv[d], mrow[d], l0);
          l1 = fmaf(hv[d + 1], mrow[d + 1], l1);
        }
        logp_s[qd * 128 + m] = l0 + l1;
      } else if (p < 2) {
        CH_CHUNK(0, 13)
      }
      SOFTBAR();

      // Phase F: softmax over 128, wave 0 | Ch chunk 2
      if (t < 64) {
        float l0 = 0.f, l1 = 0.f;
        #pragma unroll
        for (int qd = 0; qd < 4; ++qd) {
          l0 += logp_s[qd * 128 + t];
          l1 += logp_s[qd * 128 + t + 64];
        }
        float mx = fmaxf(l0, l1);
        #pragma unroll
        for (int o = 1; o < 64; o <<= 1) mx = fmaxf(mx, __shfl_xor(mx, o));
        float e0 = expf(l0 - mx), e1 = expf(l1 - mx);
        float ssum = e0 + e1;
        #pragma unroll
        for (int o = 1; o < 64; o <<= 1) ssum += __shfl_xor(ssum, o);
        float inv = 1.f / ssum;
        att_s[t] = e0 * inv;
        att_s[t + 64] = e1 * inv;
      } else if (t >= 512 && p < 2) {
        CH_CHUNK(13, 26)
      }
      SOFTBAR();

      // Phase G: x partials (2-way m-split) | Ch chunk 3
      if (t < 400) {
        int half = (t >= DD) ? 1 : 0;
        int d = t - half * DD;
        const float* as = att_s + half * 64;
        const float* mp = mem_s + (half * 64) * MEMSTRIDE + d;
        float a0 = 0.f, a1 = 0.f;
        #pragma unroll 4
        for (int m = 0; m < 64; m += 2) {
          a0 = fmaf(as[m], mp[m * MEMSTRIDE], a0);
          a1 = fmaf(as[m + 1], mp[(m + 1) * MEMSTRIDE], a1);
        }
        xp_s[half * DD + d] = a0 + a1;
      } else if (t >= 512 && p < 2) {
        CH_CHUNK(26, 39)
      }
      SOFTBAR();

      // Phase H: fc1 partials (2-way k-split) | Ch chunk 4 + gh_s write
      if (t < 400) {
        float a0 = 0.f, a1 = 0.f, a2 = 0.f, a3 = 0.f;
        if (khH == 0) {
          const f4* x0 = reinterpret_cast<const f4*>(xp_s);
          const f4* x1 = reinterpret_cast<const f4*>(xp_s + DD);
          #pragma unroll 2
          for (int k4 = 0; k4 < 50; ++k4) {
            fma4spread(a0, a1, a2, a3, wpH2[k4 * DD], x0[k4] + x1[k4]);
          }
        } else {
          const f4* qv = reinterpret_cast<const f4*>(xq_s);
          #pragma unroll 2
          for (int kk = 0; kk < 50; ++kk) {
            fma4spread(a0, a1, a2, a3, wpH2[kk * DD], qv[50 + kk]);
          }
        }
        fq_s[khH * DD + dH] = (a0 + a1) + (a2 + a3);
      } else if (t >= 512 && p < 2) {
        CH_CHUNK(39, 50)
        gh_s[gCh] = ch0;
        if (hasB) gh_s[gCh + 512] = ch1;
      }
      SOFTBAR();

      // Phase I: reduce fc1, emit on last p
      if (t < DD) {
        float qn = fq_s[t] + fq_s[DD + t] + b_fc1[t];
        qh_s[t] = qn;
        if (p == 2) {
          out[(b * JJ + j) * DD + t] = qn;
          sv_reg = mem_s[s * MEMSTRIDE + t];
          qsv_s[t] = qn + sv_reg;
        }
      }
      SOFTBAR();
    }

    // Phase K: final fc partials (2-way k-split)
    if (t < 400) {
      const f4* qv = reinterpret_cast<const f4*>(qsv_s);
      float a0 = 0.f, a1 = 0.f, a2 = 0.f, a3 = 0.f;
      #pragma unroll 5
      for (int kk = 0; kk < 25; ++kk) {
        fma4spread(a0, a1, a2, a3, wpK2[kk * DD], qv[khH * 25 + kk]);
      }
      fq_s[khH * DD + dH] = (a0 + a1) + (a2 + a3);
    }
    SOFTBAR();

    // Phase L: z, mem row update
    if (t < DD) {
      float z = tanhf(fq_s[t] + fq_s[DD + t] + 2.f * b_fc[t]);
      mem_s[s * MEMSTRIDE + t] = z * sv_reg;
    }
    SOFTBAR();
  }
}

extern "C" void kernel_launch(void* const* d_in, const int* in_sizes, int n_in,
                              void* d_out, int out_size, void* d_ws, size_t ws_size,
                              hipStream_t stream) {
  const float* cosb  = (const float*)d_in[0];
  const float* bank  = (const float*)d_in[1];
  const float* mem_a = (const float*)d_in[2];
  const float* mem_b = (const float*)d_in[3];
  const float* w_fc  = (const float*)d_in[4];
  const float* b_fc  = (const float*)d_in[5];
  const float* w_fc1 = (const float*)d_in[6];
  const float* b_fc1 = (const float*)d_in[7];
  const float* w_ih  = (const float*)d_in[8];
  const float* w_hh  = (const float*)d_in[9];
  const float* b_ih  = (const float*)d_in[10];
  const float* b_hh  = (const float*)d_in[11];

  char* ws = (char*)d_ws;
  float* Wg4   = (float*)(ws);              // 100*800*16 = 1,280,000 B
  float* Tfc14 = (float*)(ws + 1280000);    // 100*200*16 =   320,000 B
  float* Tfc4  = (float*)(ws + 1600000);    //  50*200*16 =   160,000 B
  float* bg    = (float*)(ws + 1760000);    // 800*4      =     3,200 B

  pack_gates_w<<<(100 * 800 + 255) / 256, 256, 0, stream>>>(w_ih, w_hh, b_ih, b_hh, Wg4, bg);
  pack_fc1<<<(100 * DD + 255) / 256, 256, 0, stream>>>(w_fc1, Tfc14);
  pack_fc<<<(50 * DD + 255) / 256, 256, 0, stream>>>(w_fc, Tfc4);

  int dynbytes = MM * MEMSTRIDE * sizeof(float);  // 102,912 B
  (void)hipFuncSetAttribute(reinterpret_cast<const void*>(chain_kernel),
                            hipFuncAttributeMaxDynamicSharedMemorySize, dynbytes);
  chain_kernel<<<64, TPB, dynbytes, stream>>>(cosb, bank, mem_a, mem_b, b_fc, b_fc1,
                                              (const f4*)Wg4, (const f4*)Tfc14,
                                              (const f4*)Tfc4, bg, (float*)d_out);
}